// Round 7
// baseline (947.675 us; speedup 1.0000x reference)
//
#include <hip/hip_runtime.h>

#define T_SEQ 512
#define HID   50
#define NB    4           // batch rows per block (MFMA N=16, 4 valid cols)
#define BLK   256         // 4 waves

typedef float v4f  __attribute__((ext_vector_type(4)));
typedef _Float16 f16;
typedef f16  f16x8 __attribute__((ext_vector_type(8)));

// R7: gate-INTERLEAVED M layout: m = 4*u + g  (u=unit 0..51, g=gate i,f,g,o).
// Mtile mt rows 16mt..16mt+15 = units 4mt+quad, gates r=0..3. C layout
// C[row=quad*4+r][col=n16] => lane (quad,n16) holds ALL FOUR gate preacts of
// (unit 4mt+quad, batch n16): LSTM update is an in-register MFMA epilogue.
// No gbuf, no separate update phase, 2 barriers/timestep.
// B buffer (f16 frags, 8 k-tiles of 32): tiles 0,1 = hA buf0 (+x@k62, 1@k63),
// tiles 2,3 = hA buf1, tiles 4,5 = hB buf0, tiles 6,7 = hB buf1.
// hA(t) lives in buf[t&1]; x(t+1) written into hA(t)'s buf during P0(t).
// Race-free with 2 barriers: each phase reads old-buf tiles, writes new-buf.
// MFMA 16x16x32_f16 layouts (m89/m91-verified, numerically validated R5/R6):
//   A: lane holds A[m=lane&15][k=(lane>>4)*8+j];  B: B[k=(lane>>4)*8+j][n=lane&15]

__device__ __forceinline__ float sigf(float v) {
    return __builtin_amdgcn_rcpf(1.f + __expf(-v));
}
__device__ __forceinline__ float tanh_f(float v) {
    return fmaf(2.f, __builtin_amdgcn_rcpf(1.f + __expf(-2.f * v)), -1.f);
}

__device__ __forceinline__ f16x8 ldA0(const float* __restrict__ Whh0,
                                      const float* __restrict__ Wih0,
                                      const float* __restrict__ bih0,
                                      const float* __restrict__ bhh0,
                                      int m, int kb) {
    const int u = m >> 2, g = m & 3;
    f16x8 v;
    #pragma unroll
    for (int j = 0; j < 8; ++j) {
        const int k = kb + j;
        float f = 0.f;
        if (u < HID) {
            const int rho = g * HID + u;
            if (k < HID)      f = Whh0[rho * HID + k];
            else if (k == 62) f = Wih0[rho];
            else if (k == 63) f = bih0[rho] + bhh0[rho];
        }
        v[j] = (f16)f;
    }
    return v;
}

__device__ __forceinline__ f16x8 ldA1a(const float* __restrict__ Wih1,
                                       const float* __restrict__ bih1,
                                       const float* __restrict__ bhh1,
                                       int m, int kb) {
    const int u = m >> 2, g = m & 3;
    f16x8 v;
    #pragma unroll
    for (int j = 0; j < 8; ++j) {
        const int k = kb + j;
        float f = 0.f;
        if (u < HID) {
            const int rho = g * HID + u;
            if (k < HID)      f = Wih1[rho * HID + k];
            else if (k == 63) f = bih1[rho] + bhh1[rho];
        }
        v[j] = (f16)f;
    }
    return v;
}

__global__ __launch_bounds__(BLK, 1)
void lstm2_mfma(const float* __restrict__ x,
                const float* __restrict__ Wih0,
                const float* __restrict__ Whh0,
                const float* __restrict__ bih0,
                const float* __restrict__ bhh0,
                const float* __restrict__ Wih1,
                const float* __restrict__ Whh1,
                const float* __restrict__ bih1,
                const float* __restrict__ bhh1,
                const float* __restrict__ Wfc,
                const float* __restrict__ bfc,
                float* __restrict__ out)
{
    __shared__ __align__(16) f16 AP1b[13 * 2 * 64 * 8];   // 26,624 B: Whh1 frags
    __shared__ __align__(16) f16 BPH [8 * 64 * 8];        //  8,192 B: B frags (dbuf h)
    __shared__ f16   xs16[NB][T_SEQ];                     //  4,096 B: staged x (f16)
    __shared__ float hfin[HID][NB];                       //    800 B: final hB fp32

    const int tid  = threadIdx.x;
    const int w    = tid >> 6;
    const int lane = tid & 63;
    const int n16  = lane & 15;
    const int quad = lane >> 4;
    const int bb0  = blockIdx.x * NB;
    const int nmt  = (w == 0) ? 4 : 3;              // Mtiles per wave: {4,3,3,3}
    const int mtb  = (w == 0) ? 0 : (3 * w + 1);    // first Mtile: 0,4,7,10

    const float* xg = x + (long)bb0 * T_SEQ;

    // ---- one-time: zero B frags; stage x -> f16 LDS; pack Whh1 frags ----
    for (int i = tid; i < 8 * 64 * 8; i += BLK) BPH[i] = (f16)0.f;
    for (int i = tid; i < NB * T_SEQ; i += BLK) {
        const int n = i >> 9, tt = i & (T_SEQ - 1);
        xs16[n][tt] = (f16)xg[n * T_SEQ + tt];
    }
    for (int s = tid; s < 13 * 2 * 64; s += BLK) {
        const int mt = s >> 7, kt = (s >> 6) & 1, l = s & 63;
        const int m  = mt * 16 + (l & 15);
        const int kb = kt * 32 + (l >> 4) * 8;
        const int u  = m >> 2, g = m & 3;
        f16x8 v;
        #pragma unroll
        for (int j = 0; j < 8; ++j) {
            const int k = kb + j;
            float f = 0.f;
            if (u < HID && k < HID) f = Whh1[(g * HID + u) * HID + k];
            v[j] = (f16)f;
        }
        ((f16x8*)AP1b)[s] = v;
    }

    // ---- one-time: A0 / A1a fragments into named SSA registers ----
    f16x8 a00_0 = {}, a00_1 = {}, a00_2 = {}, a00_3 = {};
    f16x8 a01_0 = {}, a01_1 = {}, a01_2 = {}, a01_3 = {};
    f16x8 aa0_0 = {}, aa0_1 = {}, aa0_2 = {}, aa0_3 = {};
    f16x8 aa1_0 = {}, aa1_1 = {}, aa1_2 = {}, aa1_3 = {};
    {
        const int m = (mtb) * 16 + n16, kb0 = quad * 8, kb1 = 32 + quad * 8;
        a00_0 = ldA0(Whh0, Wih0, bih0, bhh0, m, kb0);
        a01_0 = ldA0(Whh0, Wih0, bih0, bhh0, m, kb1);
        aa0_0 = ldA1a(Wih1, bih1, bhh1, m, kb0);
        aa1_0 = ldA1a(Wih1, bih1, bhh1, m, kb1);
    }
    {
        const int m = (mtb + 1) * 16 + n16, kb0 = quad * 8, kb1 = 32 + quad * 8;
        a00_1 = ldA0(Whh0, Wih0, bih0, bhh0, m, kb0);
        a01_1 = ldA0(Whh0, Wih0, bih0, bhh0, m, kb1);
        aa0_1 = ldA1a(Wih1, bih1, bhh1, m, kb0);
        aa1_1 = ldA1a(Wih1, bih1, bhh1, m, kb1);
    }
    {
        const int m = (mtb + 2) * 16 + n16, kb0 = quad * 8, kb1 = 32 + quad * 8;
        a00_2 = ldA0(Whh0, Wih0, bih0, bhh0, m, kb0);
        a01_2 = ldA0(Whh0, Wih0, bih0, bhh0, m, kb1);
        aa0_2 = ldA1a(Wih1, bih1, bhh1, m, kb0);
        aa1_2 = ldA1a(Wih1, bih1, bhh1, m, kb1);
    }
    if (3 < nmt) {
        const int m = (mtb + 3) * 16 + n16, kb0 = quad * 8, kb1 = 32 + quad * 8;
        a00_3 = ldA0(Whh0, Wih0, bih0, bhh0, m, kb0);
        a01_3 = ldA0(Whh0, Wih0, bih0, bhh0, m, kb1);
        aa0_3 = ldA1a(Wih1, bih1, bhh1, m, kb0);
        aa1_3 = ldA1a(Wih1, bih1, bhh1, m, kb1);
    }

    __syncthreads();
    // "1.0" bias lanes (k=63) in both hA bufs; x(0) into hA buf1 (read at t=0)
    if (tid < NB) {
        BPH[(1 * 64 + 48 + tid) * 8 + 7] = (f16)1.f;
        BPH[(3 * 64 + 48 + tid) * 8 + 7] = (f16)1.f;
        BPH[(3 * 64 + 48 + tid) * 8 + 6] = xs16[tid][0];
    }
    __syncthreads();

    float cA0 = 0.f, cA1 = 0.f, cA2 = 0.f, cA3 = 0.f;   // cell states: (unit 4mt+quad, batch n16)
    float cB0 = 0.f, cB1 = 0.f, cB2 = 0.f, cB3 = 0.f;
    const f16x8* BPF = (const f16x8*)BPH;
    const f16x8* APF = (const f16x8*)AP1b;

#define MFMA16(A, B, C) __builtin_amdgcn_mfma_f32_16x16x32_f16((A), (B), (C), 0, 0, 0)

    // in-register LSTM update: C = (i,f,g,o) preacts of (unit U, batch n16)
#define UPDW(C, CS, TBASE, U, DOFIN) { \
    const float gi = sigf(C[0]); \
    const float gf = sigf(C[1]); \
    const float gg = tanh_f(C[2]); \
    const float go = sigf(C[3]); \
    CS = fmaf(gf, CS, gi * gg); \
    const float hh = go * tanh_f(CS); \
    if ((U) < HID) { \
        BPH[(((TBASE) + ((U) >> 5)) * 64 + (((U) & 31) >> 3) * 16 + n16) * 8 + ((U) & 7)] = (f16)hh; \
        DOFIN \
    } }

#define P0MT(I) if ((I) < nmt) { \
    v4f C = {0.f, 0.f, 0.f, 0.f}; \
    C = MFMA16(a00_##I, B0, C); \
    C = MFMA16(a01_##I, B1, C); \
    const int u_ = (mtb + (I)) * 4 + quad; \
    UPDW(C, cA##I, 2 * cq, u_, {}) }

#define P1MT(I) if ((I) < nmt) { \
    f16x8 Ab0 = APF[((mtb + (I)) * 2 + 0) * 64 + lane]; \
    f16x8 Ab1 = APF[((mtb + (I)) * 2 + 1) * 64 + lane]; \
    v4f C = {0.f, 0.f, 0.f, 0.f}; \
    C = MFMA16(aa0_##I, B0, C); \
    C = MFMA16(aa1_##I, B1, C); \
    C = MFMA16(Ab0, B2, C); \
    C = MFMA16(Ab1, B3, C); \
    const int u_ = (mtb + (I)) * 4 + quad; \
    UPDW(C, cB##I, 4 + 2 * cq, u_, { if (n16 < NB) hfin[u_][n16] = hh; }) }

    #pragma clang loop unroll(disable)
    for (int t = 0; t < T_SEQ; ++t) {
        const int cq = t & 1, pq = cq ^ 1;

        // ---- P0: layer0 = [Whh0|wx|b0] @ [hA(t-1);x(t);1] -> update -> hA(t) (buf cq) ----
        {
            const f16x8 B0 = BPF[(2 * pq + 0) * 64 + lane];
            const f16x8 B1 = BPF[(2 * pq + 1) * 64 + lane];
            P0MT(0) P0MT(1) P0MT(2) P0MT(3)
        }
        // x(t+1) into hA(t)'s buf (k=62); read by P0(t+1) after 2 barriers
        if (w == 3 && lane < NB && t + 1 < T_SEQ)
            BPH[((2 * cq + 1) * 64 + 48 + lane) * 8 + 6] = xs16[lane][t + 1];
        __syncthreads();   // B1: hA(t) + x(t+1) visible

        // ---- P1: layer1 = [Wih1|b1]@[hA(t);1] + Whh1@hB(t-1) -> update -> hB(t) (buf cq) ----
        {
            const f16x8 B0 = BPF[(2 * cq + 0) * 64 + lane];
            const f16x8 B1 = BPF[(2 * cq + 1) * 64 + lane];
            const f16x8 B2 = BPF[(4 + 2 * pq + 0) * 64 + lane];
            const f16x8 B3 = BPF[(4 + 2 * pq + 1) * 64 + lane];
            P1MT(0) P1MT(1) P1MT(2) P1MT(3)
        }
        __syncthreads();   // B2: hB(t) visible (and hfin for final t)
    }

    // ---- classifier: out[n][c] = hB[n] . Wfc[c] + bfc[c] ----
    if (tid < NB * 2) {
        const int nn = tid >> 1, c = tid & 1;
        float acc = bfc[c];
        #pragma unroll
        for (int u = 0; u < HID; ++u)
            acc = fmaf(Wfc[c * HID + u], hfin[u][nn], acc);
        out[(bb0 + nn) * 2 + c] = acc;
    }
}

extern "C" void kernel_launch(void* const* d_in, const int* in_sizes, int n_in,
                              void* d_out, int out_size, void* d_ws, size_t ws_size,
                              hipStream_t stream) {
    const float* x    = (const float*)d_in[0];
    const float* Wih0 = (const float*)d_in[1];
    const float* Whh0 = (const float*)d_in[2];
    const float* bih0 = (const float*)d_in[3];
    const float* bhh0 = (const float*)d_in[4];
    const float* Wih1 = (const float*)d_in[5];
    const float* Whh1 = (const float*)d_in[6];
    const float* bih1 = (const float*)d_in[7];
    const float* bhh1 = (const float*)d_in[8];
    const float* Wfc  = (const float*)d_in[9];
    const float* bfc  = (const float*)d_in[10];
    float* out = (float*)d_out;

    const int B = in_sizes[0] / T_SEQ;   // D == 1
    const int grid = B / NB;             // 2048/4 = 512 blocks -> 2 blocks/CU

    hipLaunchKernelGGL(lstm2_mfma, dim3(grid), dim3(BLK), 0, stream,
                       x, Wih0, Whh0, bih0, bhh0, Wih1, Whh1, bih1, bhh1,
                       Wfc, bfc, out);
}

// Round 8
// 584.228 us; speedup vs baseline: 1.6221x; 1.6221x over previous
//
#include <hip/hip_runtime.h>

#define T_SEQ 512
#define HID   50
#define NB    8           // batch rows per block (MFMA N=16, 8 valid cols)
#define BLK   512         // 8 waves, grid=256 -> 1 block/CU, 2 waves/SIMD

typedef float v4f  __attribute__((ext_vector_type(4)));
typedef _Float16 f16;
typedef f16  f16x8 __attribute__((ext_vector_type(8)));

// R8 = R7 structure (gate-interleaved M: m=4u+g; in-register LSTM epilogue;
// 2 barriers/timestep; h double-buffered in B-frag tiles; bias@k63/x@k62
// folded into MFMA) with NB 4->8, BLK 256->512. R7 evidence: VALU-issue-bound
// on epilogue replicated per Mtile with 4/16 valid cols; NB=8 halves the
// per-SIMD epilogue+MFMA issue at equal occupancy (2 waves/SIMD, 256 blocks).
// B buffer (f16 frags, 8 k-tiles of 32): tiles 0,1=hA buf0 (x@k62,1@k63),
// tiles 2,3=hA buf1, tiles 4,5=hB buf0, tiles 6,7=hB buf1.
// MFMA 16x16x32_f16 layouts (m89/m91-verified; validated R5-R7):
//   A: lane holds A[m=lane&15][k=(lane>>4)*8+j];  B: B[k=(lane>>4)*8+j][n=lane&15]
//   C: lane reg r holds C[row=(lane>>4)*4+r][col=lane&15]

__device__ __forceinline__ float sigf(float v) {
    return __builtin_amdgcn_rcpf(1.f + __expf(-v));
}
__device__ __forceinline__ float tanh_f(float v) {
    return fmaf(2.f, __builtin_amdgcn_rcpf(1.f + __expf(-2.f * v)), -1.f);
}

__device__ __forceinline__ f16x8 ldA0(const float* __restrict__ Whh0,
                                      const float* __restrict__ Wih0,
                                      const float* __restrict__ bih0,
                                      const float* __restrict__ bhh0,
                                      int m, int kb) {
    const int u = m >> 2, g = m & 3;
    f16x8 v;
    #pragma unroll
    for (int j = 0; j < 8; ++j) {
        const int k = kb + j;
        float f = 0.f;
        if (u < HID) {
            const int rho = g * HID + u;
            if (k < HID)      f = Whh0[rho * HID + k];
            else if (k == 62) f = Wih0[rho];
            else if (k == 63) f = bih0[rho] + bhh0[rho];
        }
        v[j] = (f16)f;
    }
    return v;
}

__device__ __forceinline__ f16x8 ldA1a(const float* __restrict__ Wih1,
                                       const float* __restrict__ bih1,
                                       const float* __restrict__ bhh1,
                                       int m, int kb) {
    const int u = m >> 2, g = m & 3;
    f16x8 v;
    #pragma unroll
    for (int j = 0; j < 8; ++j) {
        const int k = kb + j;
        float f = 0.f;
        if (u < HID) {
            const int rho = g * HID + u;
            if (k < HID)      f = Wih1[rho * HID + k];
            else if (k == 63) f = bih1[rho] + bhh1[rho];
        }
        v[j] = (f16)f;
    }
    return v;
}

__global__ __launch_bounds__(BLK, 1)
void lstm2_mfma(const float* __restrict__ x,
                const float* __restrict__ Wih0,
                const float* __restrict__ Whh0,
                const float* __restrict__ bih0,
                const float* __restrict__ bhh0,
                const float* __restrict__ Wih1,
                const float* __restrict__ Whh1,
                const float* __restrict__ bih1,
                const float* __restrict__ bhh1,
                const float* __restrict__ Wfc,
                const float* __restrict__ bfc,
                float* __restrict__ out)
{
    __shared__ __align__(16) f16 AP1b[13 * 2 * 64 * 8];   // 26,624 B: Whh1 frags
    __shared__ __align__(16) f16 BPH [8 * 64 * 8];        //  8,192 B: B frags (dbuf h)
    __shared__ f16   xs16[NB][T_SEQ];                     //  8,192 B: staged x (f16)
    __shared__ float hfin[HID][NB];                       //  1,600 B: final hB fp32

    const int tid  = threadIdx.x;
    const int w    = tid >> 6;
    const int lane = tid & 63;
    const int n16  = lane & 15;
    const int quad = lane >> 4;
    const int bb0  = blockIdx.x * NB;
    const int nmt  = (w < 5) ? 2 : 1;               // Mtiles per wave: {2,2,2,2,2,1,1,1}
    const int mtb  = (w < 5) ? (2 * w) : (5 + w);   // first Mtile: 0,2,4,6,8,10,11,12

    const float* xg = x + (long)bb0 * T_SEQ;

    // ---- one-time: zero B frags; stage x -> f16 LDS; pack Whh1 frags ----
    for (int i = tid; i < 8 * 64 * 8; i += BLK) BPH[i] = (f16)0.f;
    for (int i = tid; i < NB * T_SEQ; i += BLK) {
        const int n = i >> 9, tt = i & (T_SEQ - 1);
        xs16[n][tt] = (f16)xg[n * T_SEQ + tt];
    }
    for (int s = tid; s < 13 * 2 * 64; s += BLK) {
        const int mt = s >> 7, kt = (s >> 6) & 1, l = s & 63;
        const int m  = mt * 16 + (l & 15);
        const int kb = kt * 32 + (l >> 4) * 8;
        const int u  = m >> 2, g = m & 3;
        f16x8 v;
        #pragma unroll
        for (int j = 0; j < 8; ++j) {
            const int k = kb + j;
            float f = 0.f;
            if (u < HID && k < HID) f = Whh1[(g * HID + u) * HID + k];
            v[j] = (f16)f;
        }
        ((f16x8*)AP1b)[s] = v;
    }

    // ---- one-time: A0 / A1a fragments into named SSA registers ----
    f16x8 a00_0 = {}, a00_1 = {};   // layer0 ktile0, Mtile 0/1 of this wave
    f16x8 a01_0 = {}, a01_1 = {};   // layer0 ktile1
    f16x8 aa0_0 = {}, aa0_1 = {};   // layer1a ktile0
    f16x8 aa1_0 = {}, aa1_1 = {};   // layer1a ktile1
    {
        const int m = (mtb) * 16 + n16, kb0 = quad * 8, kb1 = 32 + quad * 8;
        a00_0 = ldA0(Whh0, Wih0, bih0, bhh0, m, kb0);
        a01_0 = ldA0(Whh0, Wih0, bih0, bhh0, m, kb1);
        aa0_0 = ldA1a(Wih1, bih1, bhh1, m, kb0);
        aa1_0 = ldA1a(Wih1, bih1, bhh1, m, kb1);
    }
    if (nmt > 1) {
        const int m = (mtb + 1) * 16 + n16, kb0 = quad * 8, kb1 = 32 + quad * 8;
        a00_1 = ldA0(Whh0, Wih0, bih0, bhh0, m, kb0);
        a01_1 = ldA0(Whh0, Wih0, bih0, bhh0, m, kb1);
        aa0_1 = ldA1a(Wih1, bih1, bhh1, m, kb0);
        aa1_1 = ldA1a(Wih1, bih1, bhh1, m, kb1);
    }

    __syncthreads();
    // "1.0" bias lanes (k=63) in both hA bufs; x(0) into hA buf1 (read at t=0)
    if (tid < NB) {
        BPH[(1 * 64 + 48 + tid) * 8 + 7] = (f16)1.f;
        BPH[(3 * 64 + 48 + tid) * 8 + 7] = (f16)1.f;
        BPH[(3 * 64 + 48 + tid) * 8 + 6] = xs16[tid][0];
    }
    __syncthreads();

    float cA0 = 0.f, cA1 = 0.f;   // cell states: (unit 4*(mtb+I)+quad, batch n16)
    float cB0 = 0.f, cB1 = 0.f;
    const f16x8* BPF = (const f16x8*)BPH;
    const f16x8* APF = (const f16x8*)AP1b;

#define MFMA16(A, B, C) __builtin_amdgcn_mfma_f32_16x16x32_f16((A), (B), (C), 0, 0, 0)

    // in-register LSTM update: C = (i,f,g,o) preacts of (unit U, batch n16)
#define UPDW(C, CS, TBASE, U, DOFIN) { \
    const float gi = sigf(C[0]); \
    const float gf = sigf(C[1]); \
    const float gg = tanh_f(C[2]); \
    const float go = sigf(C[3]); \
    CS = fmaf(gf, CS, gi * gg); \
    const float hh = go * tanh_f(CS); \
    if ((U) < HID) { \
        BPH[(((TBASE) + ((U) >> 5)) * 64 + (((U) & 31) >> 3) * 16 + n16) * 8 + ((U) & 7)] = (f16)hh; \
        DOFIN \
    } }

#define P0MT(I) if ((I) < nmt) { \
    v4f C = {0.f, 0.f, 0.f, 0.f}; \
    C = MFMA16(a00_##I, B0, C); \
    C = MFMA16(a01_##I, B1, C); \
    const int u_ = (mtb + (I)) * 4 + quad; \
    UPDW(C, cA##I, 2 * cq, u_, {}) }

#define P1MT(I) if ((I) < nmt) { \
    f16x8 Ab0 = APF[((mtb + (I)) * 2 + 0) * 64 + lane]; \
    f16x8 Ab1 = APF[((mtb + (I)) * 2 + 1) * 64 + lane]; \
    v4f C = {0.f, 0.f, 0.f, 0.f}; \
    C = MFMA16(aa0_##I, B0, C); \
    C = MFMA16(aa1_##I, B1, C); \
    C = MFMA16(Ab0, B2, C); \
    C = MFMA16(Ab1, B3, C); \
    const int u_ = (mtb + (I)) * 4 + quad; \
    UPDW(C, cB##I, 4 + 2 * cq, u_, { if (n16 < NB) hfin[u_][n16] = hh; }) }

    #pragma clang loop unroll(disable)
    for (int t = 0; t < T_SEQ; ++t) {
        const int cq = t & 1, pq = cq ^ 1;

        // ---- P0: layer0 = [Whh0|wx|b0] @ [hA(t-1);x(t);1] -> update -> hA(t) (buf cq) ----
        {
            const f16x8 B0 = BPF[(2 * pq + 0) * 64 + lane];
            const f16x8 B1 = BPF[(2 * pq + 1) * 64 + lane];
            P0MT(0) P0MT(1)
        }
        // x(t+1) into hA(t)'s buf (k=62); read by P0(t+1), 2 barriers away
        if (w == 7 && lane < NB && t + 1 < T_SEQ)
            BPH[((2 * cq + 1) * 64 + 48 + lane) * 8 + 6] = xs16[lane][t + 1];
        __syncthreads();   // B1: hA(t) + x(t+1) visible

        // ---- P1: layer1 = [Wih1|b1]@[hA(t);1] + Whh1@hB(t-1) -> update -> hB(t) (buf cq) ----
        {
            const f16x8 B0 = BPF[(2 * cq + 0) * 64 + lane];
            const f16x8 B1 = BPF[(2 * cq + 1) * 64 + lane];
            const f16x8 B2 = BPF[(4 + 2 * pq + 0) * 64 + lane];
            const f16x8 B3 = BPF[(4 + 2 * pq + 1) * 64 + lane];
            P1MT(0) P1MT(1)
        }
        __syncthreads();   // B2: hB(t) visible (and hfin at final t)
    }

    // ---- classifier: out[n][c] = hB[n] . Wfc[c] + bfc[c] ----
    if (tid < NB * 2) {
        const int nn = tid >> 1, c = tid & 1;
        float acc = bfc[c];
        #pragma unroll
        for (int u = 0; u < HID; ++u)
            acc = fmaf(Wfc[c * HID + u], hfin[u][nn], acc);
        out[(bb0 + nn) * 2 + c] = acc;
    }
}

extern "C" void kernel_launch(void* const* d_in, const int* in_sizes, int n_in,
                              void* d_out, int out_size, void* d_ws, size_t ws_size,
                              hipStream_t stream) {
    const float* x    = (const float*)d_in[0];
    const float* Wih0 = (const float*)d_in[1];
    const float* Whh0 = (const float*)d_in[2];
    const float* bih0 = (const float*)d_in[3];
    const float* bhh0 = (const float*)d_in[4];
    const float* Wih1 = (const float*)d_in[5];
    const float* Whh1 = (const float*)d_in[6];
    const float* bih1 = (const float*)d_in[7];
    const float* bhh1 = (const float*)d_in[8];
    const float* Wfc  = (const float*)d_in[9];
    const float* bfc  = (const float*)d_in[10];
    float* out = (float*)d_out;

    const int B = in_sizes[0] / T_SEQ;   // D == 1
    const int grid = B / NB;             // 2048/8 = 256 blocks -> 1 block/CU

    hipLaunchKernelGGL(lstm2_mfma, dim3(grid), dim3(BLK), 0, stream,
                       x, Wih0, Whh0, bih0, bhh0, Wih1, Whh1, bih1, bhh1,
                       Wfc, bfc, out);
}

// Round 9
// 524.658 us; speedup vs baseline: 1.8063x; 1.1135x over previous
//
#include <hip/hip_runtime.h>

#define T_SEQ 512
#define HID   50
#define NB    8           // batch rows per block (MFMA N=16, 8 valid cols)
#define BLK   512         // 8 waves: 0-3 layer0, 4-7 layer1 (1-step skew)

typedef float v4f  __attribute__((ext_vector_type(4)));
typedef _Float16 f16;
typedef f16  f16x8 __attribute__((ext_vector_type(8)));

// R9: layer-pipelined producer/consumer. Superstep s: waves 0-3 compute
// hA(s) (layer0), waves 4-7 compute hB(s-1) (layer1). ONE barrier/superstep.
// All weights register-resident (<=16 f16x8/wave); no Whh1 LDS buffer.
// B-frag tiles (f16, 8 k-tiles of 32): 0,1=hA buf0 (x@k62,1@k63);
// 2,3=hA buf1; 4,5=hB buf0; 6,7=hB buf1.  hA(m)->buf[m&1], hB(m)->buf[m&1].
// Superstep s: rb=(s+1)&1, wb=s&1.
//  L0 reads hA(s-1)=tiles 2rb  [written s-1: 1 barrier]  writes hA(s)->2wb
//  L1 reads hA(s-1)=tiles 2rb, hB(s-2)=tiles 4+2wb [written s-1]
//     writes hB(s-1)->4+2rb  [last read s-1: WAR across 1 barrier]
//  x(s+1) written into tile 2wb+1@k62 during s; read s+1 (tiles 2rb'=2wb). OK.
// All hazards separated by >=1 barrier. Gate-interleaved M (m=4u+g), in-reg
// epilogue, bias@k63 / x@k62 folded into MFMA K-padding (validated R5-R8).
// MFMA 16x16x32_f16: A[m=lane&15][k=(lane>>4)*8+j]; B[k=(lane>>4)*8+j][n=lane&15];
// C reg r = C[row=(lane>>4)*4+r][col=lane&15].

__device__ __forceinline__ float sigf(float v) {
    return __builtin_amdgcn_rcpf(1.f + __expf(-v));
}
__device__ __forceinline__ float tanh_f(float v) {
    return fmaf(2.f, __builtin_amdgcn_rcpf(1.f + __expf(-2.f * v)), -1.f);
}

__device__ __forceinline__ f16x8 ldA0(const float* __restrict__ Whh0,
                                      const float* __restrict__ Wih0,
                                      const float* __restrict__ bih0,
                                      const float* __restrict__ bhh0,
                                      int m, int kb) {
    const int u = m >> 2, g = m & 3;
    f16x8 v;
    #pragma unroll
    for (int j = 0; j < 8; ++j) {
        const int k = kb + j;
        float f = 0.f;
        if (u < HID) {
            const int rho = g * HID + u;
            if (k < HID)      f = Whh0[rho * HID + k];
            else if (k == 62) f = Wih0[rho];
            else if (k == 63) f = bih0[rho] + bhh0[rho];
        }
        v[j] = (f16)f;
    }
    return v;
}

__device__ __forceinline__ f16x8 ldA1a(const float* __restrict__ Wih1,
                                       const float* __restrict__ bih1,
                                       const float* __restrict__ bhh1,
                                       int m, int kb) {
    const int u = m >> 2, g = m & 3;
    f16x8 v;
    #pragma unroll
    for (int j = 0; j < 8; ++j) {
        const int k = kb + j;
        float f = 0.f;
        if (u < HID) {
            const int rho = g * HID + u;
            if (k < HID)      f = Wih1[rho * HID + k];
            else if (k == 63) f = bih1[rho] + bhh1[rho];
        }
        v[j] = (f16)f;
    }
    return v;
}

__device__ __forceinline__ f16x8 ldA1b(const float* __restrict__ Whh1,
                                       int m, int kb) {
    const int u = m >> 2, g = m & 3;
    f16x8 v;
    #pragma unroll
    for (int j = 0; j < 8; ++j) {
        const int k = kb + j;
        float f = 0.f;
        if (u < HID && k < HID) f = Whh1[(g * HID + u) * HID + k];
        v[j] = (f16)f;
    }
    return v;
}

__global__ __launch_bounds__(BLK, 1)
void lstm2_mfma(const float* __restrict__ x,
                const float* __restrict__ Wih0,
                const float* __restrict__ Whh0,
                const float* __restrict__ bih0,
                const float* __restrict__ bhh0,
                const float* __restrict__ Wih1,
                const float* __restrict__ Whh1,
                const float* __restrict__ bih1,
                const float* __restrict__ bhh1,
                const float* __restrict__ Wfc,
                const float* __restrict__ bfc,
                float* __restrict__ out)
{
    __shared__ __align__(16) f16 BPH [8 * 64 * 8];   // 8,192 B: B frags (dbuf hA/hB)
    __shared__ f16   xs16[NB][T_SEQ];                // 8,192 B: staged x (f16)
    __shared__ float hfin[HID][NB];                  // 1,600 B: final hB fp32

    const int tid  = threadIdx.x;
    const int w    = tid >> 6;
    const int lane = tid & 63;
    const int n16  = lane & 15;
    const int quad = lane >> 4;
    const int bb0  = blockIdx.x * NB;
    const bool isL1 = (w >= 4);
    const int wl   = w & 3;                          // index within layer group
    const int nmt  = (wl == 0) ? 4 : 3;              // Mtiles: {4,3,3,3} per group
    const int mtb  = (wl == 0) ? 0 : (3 * wl + 1);   // first Mtile: 0,4,7,10

    const float* xg = x + (long)bb0 * T_SEQ;

    // ---- one-time: zero B frags; stage x -> f16 LDS ----
    for (int i = tid; i < 8 * 64 * 8; i += BLK) BPH[i] = (f16)0.f;
    for (int i = tid; i < NB * T_SEQ; i += BLK) {
        const int n = i >> 9, tt = i & (T_SEQ - 1);
        xs16[n][tt] = (f16)xg[n * T_SEQ + tt];
    }

    // ---- one-time: this wave's layer weights into named SSA registers ----
    f16x8 u0_0 = {}, u1_0 = {}, u2_0 = {}, u3_0 = {};
    f16x8 u0_1 = {}, u1_1 = {}, u2_1 = {}, u3_1 = {};
    f16x8 u0_2 = {}, u1_2 = {}, u2_2 = {}, u3_2 = {};
    f16x8 u0_3 = {}, u1_3 = {}, u2_3 = {}, u3_3 = {};
#define LDSET(I) if ((I) < nmt) { \
    const int m = (mtb + (I)) * 16 + n16, kb0 = quad * 8, kb1 = 32 + quad * 8; \
    if (!isL1) { \
        u0_##I = ldA0(Whh0, Wih0, bih0, bhh0, m, kb0); \
        u1_##I = ldA0(Whh0, Wih0, bih0, bhh0, m, kb1); \
    } else { \
        u0_##I = ldA1a(Wih1, bih1, bhh1, m, kb0); \
        u1_##I = ldA1a(Wih1, bih1, bhh1, m, kb1); \
        u2_##I = ldA1b(Whh1, m, kb0); \
        u3_##I = ldA1b(Whh1, m, kb1); \
    } }
    LDSET(0) LDSET(1) LDSET(2) LDSET(3)

    __syncthreads();
    // "1.0" bias lanes (k=63) in both hA bufs; x(0) into hA buf1 (read at s=0)
    if (tid < NB) {
        BPH[(1 * 64 + 48 + tid) * 8 + 7] = (f16)1.f;
        BPH[(3 * 64 + 48 + tid) * 8 + 7] = (f16)1.f;
        BPH[(3 * 64 + 48 + tid) * 8 + 6] = xs16[tid][0];
    }
    __syncthreads();

    float cs0 = 0.f, cs1 = 0.f, cs2 = 0.f, cs3 = 0.f;   // cell states (cA or cB by role)
    const f16x8* BPF = (const f16x8*)BPH;

#define MFMA16(A, B, C) __builtin_amdgcn_mfma_f32_16x16x32_f16((A), (B), (C), 0, 0, 0)

    // in-register LSTM update: C = (i,f,g,o) preacts of (unit U, batch n16)
#define UPDW(C, CS, TBASE, U, DOFIN) { \
    const float gi = sigf(C[0]); \
    const float gf = sigf(C[1]); \
    const float gg = tanh_f(C[2]); \
    const float go = sigf(C[3]); \
    CS = fmaf(gf, CS, gi * gg); \
    const float hh = go * tanh_f(CS); \
    if ((U) < HID) { \
        BPH[(((TBASE) + ((U) >> 5)) * 64 + (((U) & 31) >> 3) * 16 + n16) * 8 + ((U) & 7)] = (f16)hh; \
        DOFIN \
    } }

#define P0MT(I) if ((I) < nmt) { \
    v4f C = {0.f, 0.f, 0.f, 0.f}; \
    C = MFMA16(u0_##I, B0, C); \
    C = MFMA16(u1_##I, B1, C); \
    const int u_ = (mtb + (I)) * 4 + quad; \
    UPDW(C, cs##I, 2 * wb, u_, {}) }

#define P1MT(I) if ((I) < nmt) { \
    v4f C = {0.f, 0.f, 0.f, 0.f}; \
    C = MFMA16(u0_##I, B0, C); \
    C = MFMA16(u1_##I, B1, C); \
    C = MFMA16(u2_##I, B2, C); \
    C = MFMA16(u3_##I, B3, C); \
    const int u_ = (mtb + (I)) * 4 + quad; \
    UPDW(C, cs##I, 4 + 2 * rb, u_, \
         { if (s == T_SEQ && n16 < NB) hfin[u_][n16] = hh; }) }

    #pragma clang loop unroll(disable)
    for (int s = 0; s <= T_SEQ; ++s) {
        const int rb = (s + 1) & 1, wb = s & 1;
        if (!isL1) {
            // ---- layer0 @ s: hA(s) = upd([Whh0|wx|b0] @ [hA(s-1);x(s);1]) ----
            if (s < T_SEQ) {
                const f16x8 B0 = BPF[(2 * rb + 0) * 64 + lane];
                const f16x8 B1 = BPF[(2 * rb + 1) * 64 + lane];
                P0MT(0) P0MT(1) P0MT(2) P0MT(3)
                // x(s+1) -> hA(s)'s buf @k62; read at s+1 (1 barrier away)
                if (w == 0 && lane < NB && s + 1 < T_SEQ)
                    BPH[((2 * wb + 1) * 64 + 48 + lane) * 8 + 6] = xs16[lane][s + 1];
            }
        } else {
            // ---- layer1 @ s: hB(s-1) = upd([Wih1|b1]@[hA(s-1);1] + Whh1@hB(s-2)) ----
            if (s >= 1) {
                const f16x8 B0 = BPF[(2 * rb + 0) * 64 + lane];        // hA(s-1)
                const f16x8 B1 = BPF[(2 * rb + 1) * 64 + lane];
                const f16x8 B2 = BPF[(4 + 2 * wb + 0) * 64 + lane];    // hB(s-2)
                const f16x8 B3 = BPF[(4 + 2 * wb + 1) * 64 + lane];
                P1MT(0) P1MT(1) P1MT(2) P1MT(3)
            }
        }
        __syncthreads();   // the ONE barrier: publishes hA(s), hB(s-1), x(s+1)
    }

    // ---- classifier: out[n][c] = hB[n] . Wfc[c] + bfc[c] ----
    if (tid < NB * 2) {
        const int nn = tid >> 1, c = tid & 1;
        float acc = bfc[c];
        #pragma unroll
        for (int u = 0; u < HID; ++u)
            acc = fmaf(Wfc[c * HID + u], hfin[u][nn], acc);
        out[(bb0 + nn) * 2 + c] = acc;
    }
}

extern "C" void kernel_launch(void* const* d_in, const int* in_sizes, int n_in,
                              void* d_out, int out_size, void* d_ws, size_t ws_size,
                              hipStream_t stream) {
    const float* x    = (const float*)d_in[0];
    const float* Wih0 = (const float*)d_in[1];
    const float* Whh0 = (const float*)d_in[2];
    const float* bih0 = (const float*)d_in[3];
    const float* bhh0 = (const float*)d_in[4];
    const float* Wih1 = (const float*)d_in[5];
    const float* Whh1 = (const float*)d_in[6];
    const float* bih1 = (const float*)d_in[7];
    const float* bhh1 = (const float*)d_in[8];
    const float* Wfc  = (const float*)d_in[9];
    const float* bfc  = (const float*)d_in[10];
    float* out = (float*)d_out;

    const int B = in_sizes[0] / T_SEQ;   // D == 1
    const int grid = B / NB;             // 2048/8 = 256 blocks -> 1 block/CU

    hipLaunchKernelGGL(lstm2_mfma, dim3(grid), dim3(BLK), 0, stream,
                       x, Wih0, Whh0, bih0, bhh0, Wih1, Whh1, bih1, bhh1,
                       Wfc, bfc, out);
}

// Round 10
// 387.351 us; speedup vs baseline: 2.4466x; 1.3545x over previous
//
#include <hip/hip_runtime.h>

#define T_SEQ 512
#define HID   50
#define NB    8           // batch rows per block (MFMA N=16, cols 0-7 valid)
#define BLK   1024        // 16 waves: 0-7 layer0, 8-15 layer1 (1-step skew)

typedef float v4f  __attribute__((ext_vector_type(4)));
typedef _Float16 f16;
typedef f16  f16x8 __attribute__((ext_vector_type(8)));

// R10 = R9 layer-pipelined structure (1 barrier/superstep, dbuf hA/hB frag
// tiles, bias@k63 / x@k62 in MFMA K-padding) plus:
//  (1) Mtile-PAIR epilogue packing: cols 8-15 are garbage at NB=8, so
//      shfl_xor(8) packs two Mtiles' valid cols into one UPDW (26->16/block).
//  (2) BLK 512->1024: 16 waves, 4 waves/SIMD, <=2 Mtiles/wave (R9 evidence:
//      ~1100cyc/step unfilled stall at 2 waves/SIMD).
//  (3) Montgomery batched rcp: 4 gate denominators = 1 rcp + 9 mul
//      (10 -> 7 transcendentals/UPDW; trans measured ~16cyc = 75% of issue).
// B-frag tiles (f16, 8 k-tiles of 32): 0,1=hA buf0 (x@k62,1@k63); 2,3=hA buf1;
// 4,5=hB buf0; 6,7=hB buf1. Superstep s: rb=(s+1)&1, wb=s&1 (hazards: R9 proof).
// MFMA 16x16x32_f16: A[m=lane&15][k=(lane>>4)*8+j]; B[k=(lane>>4)*8+j][n=lane&15];
// C reg r = C[row=(lane>>4)*4+r][col=lane&15].  M layout: m=4u+g (gate-interleaved).

__device__ __forceinline__ f16x8 ldA0(const float* __restrict__ Whh0,
                                      const float* __restrict__ Wih0,
                                      const float* __restrict__ bih0,
                                      const float* __restrict__ bhh0,
                                      int m, int kb) {
    const int u = m >> 2, g = m & 3;
    f16x8 v;
    #pragma unroll
    for (int j = 0; j < 8; ++j) {
        const int k = kb + j;
        float f = 0.f;
        if (u < HID) {
            const int rho = g * HID + u;
            if (k < HID)      f = Whh0[rho * HID + k];
            else if (k == 62) f = Wih0[rho];
            else if (k == 63) f = bih0[rho] + bhh0[rho];
        }
        v[j] = (f16)f;
    }
    return v;
}

__device__ __forceinline__ f16x8 ldA1a(const float* __restrict__ Wih1,
                                       const float* __restrict__ bih1,
                                       const float* __restrict__ bhh1,
                                       int m, int kb) {
    const int u = m >> 2, g = m & 3;
    f16x8 v;
    #pragma unroll
    for (int j = 0; j < 8; ++j) {
        const int k = kb + j;
        float f = 0.f;
        if (u < HID) {
            const int rho = g * HID + u;
            if (k < HID)      f = Wih1[rho * HID + k];
            else if (k == 63) f = bih1[rho] + bhh1[rho];
        }
        v[j] = (f16)f;
    }
    return v;
}

__device__ __forceinline__ f16x8 ldA1b(const float* __restrict__ Whh1,
                                       int m, int kb) {
    const int u = m >> 2, g = m & 3;
    f16x8 v;
    #pragma unroll
    for (int j = 0; j < 8; ++j) {
        const int k = kb + j;
        float f = 0.f;
        if (u < HID && k < HID) f = Whh1[(g * HID + u) * HID + k];
        v[j] = (f16)f;
    }
    return v;
}

__global__ __launch_bounds__(BLK, 1)
void lstm2_mfma(const float* __restrict__ x,
                const float* __restrict__ Wih0,
                const float* __restrict__ Whh0,
                const float* __restrict__ bih0,
                const float* __restrict__ bhh0,
                const float* __restrict__ Wih1,
                const float* __restrict__ Whh1,
                const float* __restrict__ bih1,
                const float* __restrict__ bhh1,
                const float* __restrict__ Wfc,
                const float* __restrict__ bfc,
                float* __restrict__ out)
{
    __shared__ __align__(16) f16 BPH [8 * 64 * 8];   // 8,192 B: B frags (dbuf hA/hB)
    __shared__ f16   xs16[NB][T_SEQ];                // 8,192 B: staged x (f16)
    __shared__ float hfin[HID][NB];                  // 1,600 B: final hB fp32

    const int tid  = threadIdx.x;
    const int w    = tid >> 6;
    const int lane = tid & 63;
    const int n16  = lane & 15;
    const int quad = lane >> 4;
    const int bb0  = blockIdx.x * NB;
    const bool isL1 = (w >= 8);
    const int g8   = w & 7;                          // index within layer group
    const int nmt  = (g8 < 5) ? 2 : 1;               // Mtiles: {2,2,2,2,2,1,1,1}
    const int mtb  = (g8 < 5) ? (2 * g8) : (5 + g8); // first Mtile: 0,2,4,6,8,10,11,12

    const float* xg = x + (long)bb0 * T_SEQ;

    // ---- one-time: zero B frags; stage x -> f16 LDS ----
    for (int i = tid; i < 8 * 64 * 8; i += BLK) BPH[i] = (f16)0.f;
    for (int i = tid; i < NB * T_SEQ; i += BLK) {
        const int n = i >> 9, tt = i & (T_SEQ - 1);
        xs16[n][tt] = (f16)xg[n * T_SEQ + tt];
    }

    // ---- one-time: this wave's layer weights into named SSA registers ----
    f16x8 u0_0 = {}, u1_0 = {}, u2_0 = {}, u3_0 = {};
    f16x8 u0_1 = {}, u1_1 = {}, u2_1 = {}, u3_1 = {};
#define LDSET(I) if ((I) < nmt) { \
    const int m = (mtb + (I)) * 16 + n16, kb0 = quad * 8, kb1 = 32 + quad * 8; \
    if (!isL1) { \
        u0_##I = ldA0(Whh0, Wih0, bih0, bhh0, m, kb0); \
        u1_##I = ldA0(Whh0, Wih0, bih0, bhh0, m, kb1); \
    } else { \
        u0_##I = ldA1a(Wih1, bih1, bhh1, m, kb0); \
        u1_##I = ldA1a(Wih1, bih1, bhh1, m, kb1); \
        u2_##I = ldA1b(Whh1, m, kb0); \
        u3_##I = ldA1b(Whh1, m, kb1); \
    } }
    LDSET(0) LDSET(1)

    __syncthreads();
    // "1.0" bias lanes (k=63) in both hA bufs; x(0) into hA buf1 (read at s=0)
    if (tid < NB) {
        BPH[(1 * 64 + 48 + tid) * 8 + 7] = (f16)1.f;
        BPH[(3 * 64 + 48 + tid) * 8 + 7] = (f16)1.f;
        BPH[(3 * 64 + 48 + tid) * 8 + 6] = xs16[tid][0];
    }
    __syncthreads();

    // per-lane cell state: (unit u_, batch n16&7); u_ fixed per lane all steps
    const int u_ = (mtb + ((nmt == 2 && n16 >= 8) ? 1 : 0)) * 4 + quad;
    const bool valid = (u_ < HID) && (nmt == 2 || n16 < 8);
    float cs = 0.f;
    const f16x8* BPF = (const f16x8*)BPH;

#define MFMA16(A, B, C) __builtin_amdgcn_mfma_f32_16x16x32_f16((A), (B), (C), 0, 0, 0)

    // packed LSTM epilogue: CC = (i,f,g,o) preacts of (unit u_, batch n16&7).
    // Montgomery batch-inversion: 1 rcp for the 4 gate denominators.
#define UPDW2(C, TBASE, DOFIN) { \
    const float e1 = __expf(-C.x); \
    const float e2 = __expf(-C.y); \
    const float e3 = __expf(-2.f * C.z); \
    const float e4 = __expf(-C.w); \
    const float d1 = 1.f + e1, d2 = 1.f + e2, d3 = 1.f + e3, d4 = 1.f + e4; \
    const float p2 = d1 * d2, p3 = p2 * d3, p4 = p3 * d4; \
    const float i4 = __builtin_amdgcn_rcpf(p4); \
    const float go = i4 * p3;                 /* 1/d4 */ \
    const float i3 = i4 * d4; \
    const float r3 = i3 * p2;                 /* 1/d3 */ \
    const float i2 = i3 * d3; \
    const float gf = i2 * d1;                 /* 1/d2 */ \
    const float gi = i2 * d2;                 /* 1/d1 */ \
    const float gg = fmaf(2.f, r3, -1.f); \
    cs = fmaf(gf, cs, gi * gg); \
    const float th = fmaf(2.f, __builtin_amdgcn_rcpf(1.f + __expf(-2.f * cs)), -1.f); \
    const float hh = go * th; \
    if (valid) { \
        BPH[(((TBASE) + (u_ >> 5)) * 64 + ((u_ & 31) >> 3) * 16 + (n16 & 7)) * 8 + (u_ & 7)] = (f16)hh; \
        DOFIN \
    } }

    #pragma clang loop unroll(disable)
    for (int s = 0; s <= T_SEQ; ++s) {
        const int rb = (s + 1) & 1, wb = s & 1;
        if (!isL1) {
            // ---- layer0 @ s: hA(s) = upd([Whh0|wx|b0] @ [hA(s-1);x(s);1]) ----
            if (s < T_SEQ) {
                const f16x8 B0 = BPF[(2 * rb + 0) * 64 + lane];
                const f16x8 B1 = BPF[(2 * rb + 1) * 64 + lane];
                v4f C0 = {0.f, 0.f, 0.f, 0.f};
                C0 = MFMA16(u0_0, B0, C0);
                C0 = MFMA16(u1_0, B1, C0);
                v4f CC = C0;
                if (nmt == 2) {
                    v4f C1 = {0.f, 0.f, 0.f, 0.f};
                    C1 = MFMA16(u0_1, B0, C1);
                    C1 = MFMA16(u1_1, B1, C1);
                    const float sx = __shfl_xor(C1.x, 8);
                    const float sy = __shfl_xor(C1.y, 8);
                    const float sz = __shfl_xor(C1.z, 8);
                    const float sw = __shfl_xor(C1.w, 8);
                    CC.x = (n16 < 8) ? C0.x : sx;
                    CC.y = (n16 < 8) ? C0.y : sy;
                    CC.z = (n16 < 8) ? C0.z : sz;
                    CC.w = (n16 < 8) ? C0.w : sw;
                }
                UPDW2(CC, 2 * wb, {})
                // x(s+1) -> hA(s)'s buf @k62; read at s+1 (1 barrier away)
                if (w == 0 && lane < NB && s + 1 < T_SEQ)
                    BPH[((2 * wb + 1) * 64 + 48 + lane) * 8 + 6] = xs16[lane][s + 1];
            }
        } else {
            // ---- layer1 @ s: hB(s-1) = upd([Wih1|b1]@[hA(s-1);1] + Whh1@hB(s-2)) ----
            if (s >= 1) {
                const f16x8 B0 = BPF[(2 * rb + 0) * 64 + lane];        // hA(s-1)
                const f16x8 B1 = BPF[(2 * rb + 1) * 64 + lane];
                const f16x8 B2 = BPF[(4 + 2 * wb + 0) * 64 + lane];    // hB(s-2)
                const f16x8 B3 = BPF[(4 + 2 * wb + 1) * 64 + lane];
                v4f C0 = {0.f, 0.f, 0.f, 0.f};
                C0 = MFMA16(u0_0, B0, C0);
                C0 = MFMA16(u1_0, B1, C0);
                C0 = MFMA16(u2_0, B2, C0);
                C0 = MFMA16(u3_0, B3, C0);
                v4f CC = C0;
                if (nmt == 2) {
                    v4f C1 = {0.f, 0.f, 0.f, 0.f};
                    C1 = MFMA16(u0_1, B0, C1);
                    C1 = MFMA16(u1_1, B1, C1);
                    C1 = MFMA16(u2_1, B2, C1);
                    C1 = MFMA16(u3_1, B3, C1);
                    const float sx = __shfl_xor(C1.x, 8);
                    const float sy = __shfl_xor(C1.y, 8);
                    const float sz = __shfl_xor(C1.z, 8);
                    const float sw = __shfl_xor(C1.w, 8);
                    CC.x = (n16 < 8) ? C0.x : sx;
                    CC.y = (n16 < 8) ? C0.y : sy;
                    CC.z = (n16 < 8) ? C0.z : sz;
                    CC.w = (n16 < 8) ? C0.w : sw;
                }
                UPDW2(CC, 4 + 2 * rb,
                      { if (s == T_SEQ) hfin[u_][n16 & 7] = hh; })
            }
        }
        __syncthreads();   // the ONE barrier: publishes hA(s), hB(s-1), x(s+1)
    }

    // ---- classifier: out[n][c] = hB[n] . Wfc[c] + bfc[c] ----
    if (tid < NB * 2) {
        const int nn = tid >> 1, c = tid & 1;
        float acc = bfc[c];
        #pragma unroll
        for (int u = 0; u < HID; ++u)
            acc = fmaf(Wfc[c * HID + u], hfin[u][nn], acc);
        out[(bb0 + nn) * 2 + c] = acc;
    }
}

extern "C" void kernel_launch(void* const* d_in, const int* in_sizes, int n_in,
                              void* d_out, int out_size, void* d_ws, size_t ws_size,
                              hipStream_t stream) {
    const float* x    = (const float*)d_in[0];
    const float* Wih0 = (const float*)d_in[1];
    const float* Whh0 = (const float*)d_in[2];
    const float* bih0 = (const float*)d_in[3];
    const float* bhh0 = (const float*)d_in[4];
    const float* Wih1 = (const float*)d_in[5];
    const float* Whh1 = (const float*)d_in[6];
    const float* bih1 = (const float*)d_in[7];
    const float* bhh1 = (const float*)d_in[8];
    const float* Wfc  = (const float*)d_in[9];
    const float* bfc  = (const float*)d_in[10];
    float* out = (float*)d_out;

    const int B = in_sizes[0] / T_SEQ;   // D == 1
    const int grid = B / NB;             // 2048/8 = 256 blocks -> 1 block/CU

    hipLaunchKernelGGL(lstm2_mfma, dim3(grid), dim3(BLK), 0, stream,
                       x, Wih0, Whh0, bih0, bhh0, Wih1, Whh1, bih1, bhh1,
                       Wfc, bfc, out);
}